// Round 1
// baseline (192.635 us; speedup 1.0000x reference)
//
#include <hip/hip_runtime.h>
#include <hip/hip_bf16.h>
#include <stdint.h>

#define BB 4
#define SS 2048
#define DD 512
#define HH 512

typedef __attribute__((ext_vector_type(8))) short short8;
typedef __attribute__((ext_vector_type(4))) float floatx4;

typedef __attribute__((address_space(3))) uint32_t lds_u32_t;
typedef const __attribute__((address_space(1))) uint32_t glb_u32_t;

__device__ __forceinline__ void gload_lds16(const void* g, void* l) {
  __builtin_amdgcn_global_load_lds((glb_u32_t*)g, (lds_u32_t*)l, 16, 0, 0);
}

__device__ __forceinline__ short f2bf(float f) {
  __hip_bfloat16 h = __float2bfloat16(f);
  return __builtin_bit_cast(short, h);
}

// ---------------- GEMM: C = A * B^T (+bias)(+sigmoid) ----------------
// A: [M,K] bf16 (lda), B: [N,K] bf16 (ldb), C: [M,N] (ldc)
// EPI: 0 = plain -> bf16 out, 1 = +bias -> bf16, 2 = sigmoid(v+bias) -> bf16,
//      3 = plain -> f32 out
template <int BM, int EPI>
__global__ __launch_bounds__(256) void gemm_bt(
    const short* __restrict__ A, const short* __restrict__ Bm,
    void* __restrict__ Cm, const float* __restrict__ bias, int K, int lda,
    int ldb, int ldc, long sA, long sB, long sC) {
  constexpr int BN = 128;
  constexpr int BK = 32;
  constexpr int MF = BM / 32;  // 16x16 m-fragments per wave
  __shared__ short As[BM * BK];
  __shared__ short Bs[BN * BK];

  const int bz = blockIdx.z;
  const long row0 = (long)blockIdx.x * BM;
  const long col0 = (long)blockIdx.y * BN;
  const short* Ab = A + bz * sA + row0 * lda;
  const short* Bb = Bm + bz * sB + col0 * ldb;

  const int t = threadIdx.x;
  const int lane = t & 63;
  const int wid = t >> 6;
  const int wr = wid >> 1, wc = wid & 1;  // 2x2 wave grid
  const int r16 = lane & 15;
  const int kc = (lane >> 4) * 8;  // k element offset for fragments

  const int st_row = t >> 2;       // staging: row within 64-row slab
  const int st_k = (t & 3) * 8;    // staging: k element offset (16B chunk)

  floatx4 acc[MF][4];
#pragma unroll
  for (int i = 0; i < MF; i++)
#pragma unroll
    for (int j = 0; j < 4; j++) acc[i][j] = (floatx4)0.f;

  for (int k0 = 0; k0 < K; k0 += BK) {
#pragma unroll
    for (int i = 0; i < BM / 64; i++)
      gload_lds16(Ab + (long)(i * 64 + st_row) * lda + k0 + st_k,
                  &As[(i * 64 + st_row) * BK + st_k]);
#pragma unroll
    for (int i = 0; i < 2; i++)
      gload_lds16(Bb + (long)(i * 64 + st_row) * ldb + k0 + st_k,
                  &Bs[(i * 64 + st_row) * BK + st_k]);
    __syncthreads();

    short8 af[MF], bfr[4];
#pragma unroll
    for (int i = 0; i < MF; i++)
      af[i] = *(const short8*)&As[(wr * (BM / 2) + i * 16 + r16) * BK + kc];
#pragma unroll
    for (int j = 0; j < 4; j++)
      bfr[j] = *(const short8*)&Bs[(wc * 64 + j * 16 + r16) * BK + kc];
#pragma unroll
    for (int i = 0; i < MF; i++)
#pragma unroll
      for (int j = 0; j < 4; j++)
        acc[i][j] = __builtin_amdgcn_mfma_f32_16x16x32_bf16(af[i], bfr[j],
                                                            acc[i][j], 0, 0, 0);
    __syncthreads();
  }

  // Epilogue. C/D layout: col = lane&15, row = (lane>>4)*4 + reg.
#pragma unroll
  for (int i = 0; i < MF; i++) {
    const long rbase = row0 + wr * (BM / 2) + i * 16 + (lane >> 4) * 4;
#pragma unroll
    for (int j = 0; j < 4; j++) {
      const long col = col0 + wc * 64 + j * 16 + r16;
      float bv = 0.f;
      if (EPI == 1 || EPI == 2) bv = bias[col];
#pragma unroll
      for (int rg = 0; rg < 4; rg++) {
        float v = acc[i][j][rg];
        if (EPI == 1) v += bv;
        if (EPI == 2) v = 1.f / (1.f + __expf(-(v + bv)));
        const long idx = bz * sC + (rbase + rg) * ldc + col;
        if (EPI == 3)
          ((float*)Cm)[idx] = v;
        else
          ((__hip_bfloat16*)Cm)[idx] = __float2bfloat16(v);
      }
    }
  }
}

// ---------------- conversions ----------------
__global__ void cvt_bf16(const float* __restrict__ in, short* __restrict__ out,
                         int n4) {
  int i = blockIdx.x * blockDim.x + threadIdx.x;
  int stride = gridDim.x * blockDim.x;
  for (; i < n4; i += stride) {
    float4 v = ((const float4*)in)[i];
    short o[4] = {f2bf(v.x), f2bf(v.y), f2bf(v.z), f2bf(v.w)};
    *(uint64_t*)&out[i * 4] = *(uint64_t*)o;
  }
}

// in: f32 [R][C] (+batch), out: bf16 [C][R] (+batch)
__global__ void tr_cvt(const float* __restrict__ in, short* __restrict__ out,
                       int R, int C) {
  __shared__ float tile[32][33];
  const long b = blockIdx.z;
  in += b * (long)R * C;
  out += b * (long)R * C;
  const int c0 = blockIdx.x * 32, r0 = blockIdx.y * 32;
  const int tx = threadIdx.x, ty = threadIdx.y;  // (32, 8)
#pragma unroll
  for (int i = 0; i < 32; i += 8)
    tile[ty + i][tx] = in[(long)(r0 + ty + i) * C + c0 + tx];
  __syncthreads();
#pragma unroll
  for (int i = 0; i < 32; i += 8)
    out[(long)(c0 + ty + i) * R + r0 + tx] = f2bf(tile[tx][ty + i]);
}

__global__ void bias_cat(const float* __restrict__ bq,
                         const float* __restrict__ bk,
                         const float* __restrict__ bv,
                         float* __restrict__ bcat) {
  int i = blockIdx.x * blockDim.x + threadIdx.x;
  if (i < 512)
    bcat[i] = bq[i];
  else if (i < 1024)
    bcat[i] = bk[i - 512];
  else if (i < 1536)
    bcat[i] = bv[i - 1024];
}

extern "C" void kernel_launch(void* const* d_in, const int* in_sizes, int n_in,
                              void* d_out, int out_size, void* d_ws,
                              size_t ws_size, hipStream_t stream) {
  (void)in_sizes;
  (void)n_in;
  (void)out_size;
  (void)ws_size;
  const float* x = (const float*)d_in[0];
  const float* Wq = (const float*)d_in[1];
  const float* bq = (const float*)d_in[2];
  const float* Wk = (const float*)d_in[3];
  const float* bk = (const float*)d_in[4];
  const float* Wv = (const float*)d_in[5];
  const float* bv = (const float*)d_in[6];
  const float* Wd = (const float*)d_in[7];
  const float* bd = (const float*)d_in[8];

  // workspace layout (bf16 = short)
  char* w = (char*)d_ws;
  auto alloc = [&](size_t bytes) {
    char* p = w;
    w += (bytes + 255) & ~(size_t)255;
    return p;
  };
  short* xb = (short*)alloc((size_t)BB * SS * DD * 2);     // x bf16, reused as dense
  short* xT = (short*)alloc((size_t)BB * DD * SS * 2);     // x^T per batch [D][S]
  short* WT = (short*)alloc((size_t)3 * HH * DD * 2);      // [Wq^T;Wk^T;Wv^T] [1536][512]
  short* WdT = (short*)alloc((size_t)HH * SS * 2);         // Wd^T [512][2048]
  float* bcat = (float*)alloc((size_t)3 * HH * 4);         // [1536]
  short* qkv = (short*)alloc((size_t)BB * SS * 3 * HH * 2);  // [8192][1536]
  short* qk = (short*)alloc((size_t)BB * SS * SS * 2);     // [4][2048][2048], reused for vw
  short* dense = xb;   // alias: xb dead after stage 1
  short* vw = qk;      // alias: qk dead after stage 3

  dim3 tb(32, 8);
  // x -> bf16
  cvt_bf16<<<2048, 256, 0, stream>>>(x, xb, BB * SS * DD / 4);
  // weight transposes (to [N][K] bf16)
  tr_cvt<<<dim3(HH / 32, DD / 32, 1), tb, 0, stream>>>(Wq, WT + 0 * HH * DD, DD, HH);
  tr_cvt<<<dim3(HH / 32, DD / 32, 1), tb, 0, stream>>>(Wk, WT + 1 * HH * DD, DD, HH);
  tr_cvt<<<dim3(HH / 32, DD / 32, 1), tb, 0, stream>>>(Wv, WT + 2 * HH * DD, DD, HH);
  tr_cvt<<<dim3(HH / 32, SS / 32, 1), tb, 0, stream>>>(Wd, WdT, SS, HH);
  tr_cvt<<<dim3(DD / 32, SS / 32, BB), tb, 0, stream>>>(x, xT, SS, DD);
  bias_cat<<<6, 256, 0, stream>>>(bq, bk, bv, bcat);

  // Stage 1: qkv = x @ [Wq|Wk|Wv] + bias   [8192,1536] K=512
  gemm_bt<128, 1><<<dim3(BB * SS / 128, 1536 / 128, 1), 256, 0, stream>>>(
      xb, WT, qkv, bcat, DD, DD, DD, 3 * HH, 0, 0, 0);
  // Stage 2: qk[b] = q[b] @ k[b]^T   [2048,2048] K=512, batch 4
  gemm_bt<128, 0><<<dim3(SS / 128, SS / 128, BB), 256, 0, stream>>>(
      qkv + 0, qkv + HH, qk, nullptr, HH, 3 * HH, 3 * HH, SS,
      (long)SS * 3 * HH, (long)SS * 3 * HH, (long)SS * SS);
  // Stage 3: dense = sigmoid(qk @ Wd^T^T + bd)   [8192,512] K=2048
  gemm_bt<64, 2><<<dim3(BB * SS / 64, HH / 128, 1), 256, 0, stream>>>(
      qk, WdT, dense, bd, SS, SS, SS, HH, 0, 0, 0);
  // Stage 4: vw[b] = dense[b] @ v[b]^T   [2048,2048] K=512, batch 4
  gemm_bt<128, 0><<<dim3(SS / 128, SS / 128, BB), 256, 0, stream>>>(
      dense, qkv + 2 * HH, vw, nullptr, HH, HH, 3 * HH, SS, (long)SS * HH,
      (long)SS * 3 * HH, (long)SS * SS);
  // Stage 5: out[b] = vw[b] @ x[b]  (= vw @ (x^T)^T)  [2048,512] K=2048, f32 out
  gemm_bt<64, 3><<<dim3(SS / 64, DD / 128, BB), 256, 0, stream>>>(
      vw, xT, d_out, nullptr, SS, SS, SS, DD, (long)SS * SS, (long)DD * SS,
      (long)SS * DD);
}

// Round 2
// 126.294 us; speedup vs baseline: 1.5253x; 1.5253x over previous
//
#include <hip/hip_runtime.h>
#include <hip/hip_bf16.h>
#include <stdint.h>

#define BB 4
#define SS 2048
#define DD 512
#define HH 512

typedef __attribute__((ext_vector_type(8))) short short8;
typedef __attribute__((ext_vector_type(4))) float floatx4;

typedef __attribute__((address_space(3))) uint32_t lds_u32_t;
typedef const __attribute__((address_space(1))) uint32_t glb_u32_t;

__device__ __forceinline__ void gload_lds16(const void* g, void* l) {
  __builtin_amdgcn_global_load_lds((glb_u32_t*)g, (lds_u32_t*)l, 16, 0, 0);
}

__device__ __forceinline__ short f2bf(float f) {
  __hip_bfloat16 h = __float2bfloat16(f);
  return __builtin_bit_cast(short, h);
}

// ---------------- GEMM core: C = A * B^T (+bias)(+sigmoid) ----------------
// A: [M,K] bf16 (lda), B: [N,K] bf16 (ldb), C tile at (row0, col0), ldc.
// EPI: 0 = plain -> bf16, 1 = +bias -> bf16, 2 = sigmoid(v+bias) -> bf16,
//      3 = plain -> f32
template <int BM, int EPI>
__device__ __forceinline__ void gemm_core(
    const short* __restrict__ A, const short* __restrict__ Bm,
    void* __restrict__ Cm, long c_base, const float* __restrict__ bias, int K,
    int lda, int ldb, int ldc, long row0, long col0) {
  constexpr int BN = 128;
  constexpr int BK = 32;
  constexpr int MF = BM / 32;  // 16x16 m-fragments per wave (per wr half)
  __shared__ short As[BM * BK];
  __shared__ short Bs[BN * BK];

  const short* Ab = A + row0 * lda;
  const short* Bb = Bm + col0 * ldb;

  const int t = threadIdx.x;
  const int lane = t & 63;
  const int wid = t >> 6;
  const int wr = wid >> 1, wc = wid & 1;  // 2x2 wave grid
  const int r16 = lane & 15;
  const int kc = (lane >> 4) * 8;  // k element offset for fragments

  const int st_row = t >> 2;     // staging: row within 64-row slab
  const int st_k = (t & 3) * 8;  // staging: k element offset (16B chunk)

  floatx4 acc[MF][4];
#pragma unroll
  for (int i = 0; i < MF; i++)
#pragma unroll
    for (int j = 0; j < 4; j++) acc[i][j] = (floatx4)0.f;

  for (int k0 = 0; k0 < K; k0 += BK) {
#pragma unroll
    for (int i = 0; i < BM / 64; i++)
      gload_lds16(Ab + (long)(i * 64 + st_row) * lda + k0 + st_k,
                  &As[(i * 64 + st_row) * BK + st_k]);
#pragma unroll
    for (int i = 0; i < 2; i++)
      gload_lds16(Bb + (long)(i * 64 + st_row) * ldb + k0 + st_k,
                  &Bs[(i * 64 + st_row) * BK + st_k]);
    __syncthreads();

    short8 af[MF], bfr[4];
#pragma unroll
    for (int i = 0; i < MF; i++)
      af[i] = *(const short8*)&As[(wr * (BM / 2) + i * 16 + r16) * BK + kc];
#pragma unroll
    for (int j = 0; j < 4; j++)
      bfr[j] = *(const short8*)&Bs[(wc * 64 + j * 16 + r16) * BK + kc];
#pragma unroll
    for (int i = 0; i < MF; i++)
#pragma unroll
      for (int j = 0; j < 4; j++)
        acc[i][j] = __builtin_amdgcn_mfma_f32_16x16x32_bf16(af[i], bfr[j],
                                                            acc[i][j], 0, 0, 0);
    __syncthreads();
  }

  // Epilogue. C/D layout: col = lane&15, row = (lane>>4)*4 + reg.
#pragma unroll
  for (int i = 0; i < MF; i++) {
    const long rbase = row0 + wr * (BM / 2) + i * 16 + (lane >> 4) * 4;
#pragma unroll
    for (int j = 0; j < 4; j++) {
      const long col = col0 + wc * 64 + j * 16 + r16;
      float bv = 0.f;
      if (EPI == 1 || EPI == 2) bv = bias[col];
#pragma unroll
      for (int rg = 0; rg < 4; rg++) {
        float v = acc[i][j][rg];
        if (EPI == 1) v += bv;
        if (EPI == 2) v = 1.f / (1.f + __expf(-(v + bv)));
        const long idx = c_base + (rbase + rg) * ldc + col;
        if (EPI == 3)
          ((float*)Cm)[idx] = v;
        else
          ((__hip_bfloat16*)Cm)[idx] = __float2bfloat16(v);
      }
    }
  }
}

template <int BM, int EPI>
__global__ __launch_bounds__(256) void gemm_bt(
    const short* __restrict__ A, const short* __restrict__ Bm,
    void* __restrict__ Cm, const float* __restrict__ bias, int K, int lda,
    int ldb, int ldc, long sA, long sB, long sC) {
  const int bz = blockIdx.z;
  gemm_core<BM, EPI>(A + bz * sA, Bm + bz * sB, Cm, bz * sC, bias, K, lda, ldb,
                     ldc, (long)blockIdx.x * BM, (long)blockIdx.y * 128);
}

// Dual small-M, K=2048 launch: task 0: M2[b] = Wd^T @ k[b] (= gemm_bt(WdT,kT))
//                              task 1: M3t[b] = x^T @ v[b] (= gemm_bt(xT,vT))
__global__ __launch_bounds__(256) void gemm_dual(
    const short* __restrict__ WdT, const short* __restrict__ kT,
    short* __restrict__ M2, const short* __restrict__ xT,
    const short* __restrict__ vT, short* __restrict__ M3t) {
  const int bz = blockIdx.z;
  const int task = bz >> 2, b = bz & 3;
  const short* A = task ? xT + (long)b * HH * SS : WdT;
  const short* B = (task ? vT : kT) + (long)b * HH * SS;
  short* C = (task ? M3t : M2) + (long)b * HH * HH;
  gemm_core<128, 0>(A, B, C, 0, nullptr, SS, SS, SS, HH,
                    (long)blockIdx.x * 128, (long)blockIdx.y * 128);
}

// ---------------- conversions ----------------
__global__ void cvt_bf16(const float* __restrict__ in, short* __restrict__ out,
                         int n4) {
  int i = blockIdx.x * blockDim.x + threadIdx.x;
  int stride = gridDim.x * blockDim.x;
  for (; i < n4; i += stride) {
    float4 v = ((const float4*)in)[i];
    short o[4] = {f2bf(v.x), f2bf(v.y), f2bf(v.z), f2bf(v.w)};
    *(uint64_t*)&out[i * 4] = *(uint64_t*)o;
  }
}

// in: f32 [R][C], out: bf16 [C][R] (+batch via z)
__global__ void tr_cvt(const float* __restrict__ in, short* __restrict__ out,
                       int R, int C) {
  __shared__ float tile[32][33];
  const long b = blockIdx.z;
  in += b * (long)R * C;
  out += b * (long)R * C;
  const int c0 = blockIdx.x * 32, r0 = blockIdx.y * 32;
  const int tx = threadIdx.x, ty = threadIdx.y;  // (32, 8)
#pragma unroll
  for (int i = 0; i < 32; i += 8)
    tile[ty + i][tx] = in[(long)(r0 + ty + i) * C + c0 + tx];
  __syncthreads();
#pragma unroll
  for (int i = 0; i < 32; i += 8)
    out[(long)(c0 + ty + i) * R + r0 + tx] = f2bf(tile[tx][ty + i]);
}

// Wq|Wk|Wv [512][512] f32 -> WT [3*512][512] bf16 transposed, z selects W
__global__ void trW3(const float* __restrict__ Wq, const float* __restrict__ Wk,
                     const float* __restrict__ Wv, short* __restrict__ WT) {
  __shared__ float tile[32][33];
  const int z = blockIdx.z;
  const float* in = z == 0 ? Wq : (z == 1 ? Wk : Wv);
  short* out = WT + (long)z * HH * DD;
  const int c0 = blockIdx.x * 32, r0 = blockIdx.y * 32;
  const int tx = threadIdx.x, ty = threadIdx.y;
#pragma unroll
  for (int i = 0; i < 32; i += 8)
    tile[ty + i][tx] = in[(long)(r0 + ty + i) * HH + c0 + tx];
  __syncthreads();
#pragma unroll
  for (int i = 0; i < 32; i += 8)
    out[(long)(c0 + ty + i) * DD + r0 + tx] = f2bf(tile[tx][ty + i]);
}

// k,v slices of qkv -> kT,vT [512][2048] bf16 per batch. z: (which<<2)|b
__global__ void tr_kv(const short* __restrict__ qkv, short* __restrict__ kT,
                      short* __restrict__ vT) {
  __shared__ short tile[32][34];
  const int z = blockIdx.z;
  const int which = z >> 2, b = z & 3;
  const short* in = qkv + (long)b * SS * (3 * HH) + (1 + which) * HH;
  short* out = (which ? vT : kT) + (long)b * HH * SS;
  const int c0 = blockIdx.x * 32, r0 = blockIdx.y * 32;
  const int tx = threadIdx.x, ty = threadIdx.y;  // (32, 8)
#pragma unroll
  for (int i = 0; i < 32; i += 8)
    tile[ty + i][tx] = in[(long)(r0 + ty + i) * (3 * HH) + c0 + tx];
  __syncthreads();
#pragma unroll
  for (int i = 0; i < 32; i += 8)
    out[(long)(c0 + ty + i) * SS + r0 + tx] = tile[tx][ty + i];
}

__global__ void bias_cat(const float* __restrict__ bq,
                         const float* __restrict__ bk,
                         const float* __restrict__ bv,
                         float* __restrict__ bcat) {
  int i = blockIdx.x * blockDim.x + threadIdx.x;
  if (i < 512)
    bcat[i] = bq[i];
  else if (i < 1024)
    bcat[i] = bk[i - 512];
  else if (i < 1536)
    bcat[i] = bv[i - 1024];
}

extern "C" void kernel_launch(void* const* d_in, const int* in_sizes, int n_in,
                              void* d_out, int out_size, void* d_ws,
                              size_t ws_size, hipStream_t stream) {
  (void)in_sizes;
  (void)n_in;
  (void)out_size;
  (void)ws_size;
  const float* x = (const float*)d_in[0];
  const float* Wq = (const float*)d_in[1];
  const float* bq = (const float*)d_in[2];
  const float* Wk = (const float*)d_in[3];
  const float* bk = (const float*)d_in[4];
  const float* Wv = (const float*)d_in[5];
  const float* bv = (const float*)d_in[6];
  const float* Wd = (const float*)d_in[7];
  const float* bd = (const float*)d_in[8];

  char* w = (char*)d_ws;
  auto alloc = [&](size_t bytes) {
    char* p = w;
    w += (bytes + 255) & ~(size_t)255;
    return p;
  };
  short* xb = (short*)alloc((size_t)BB * SS * DD * 2);    // 8MB; reused as dense
  short* xT = (short*)alloc((size_t)BB * DD * SS * 2);    // 8MB [b][D][S]
  short* WT = (short*)alloc((size_t)3 * HH * DD * 2);     // 1.5MB [1536][512]
  short* WdT = (short*)alloc((size_t)HH * SS * 2);        // 2MB [512][2048]
  float* bcat = (float*)alloc((size_t)3 * HH * 4);        // [1536]
  short* qkv = (short*)alloc((size_t)BB * SS * 3 * HH * 2);  // 24MB [8192][1536]
  short* kT = (short*)alloc((size_t)BB * HH * SS * 2);    // 8MB [b][H][S]
  short* vT = (short*)alloc((size_t)BB * HH * SS * 2);    // 8MB [b][H][S]
  short* M2 = (short*)alloc((size_t)BB * HH * HH * 2);    // 2MB [b][H'][H]
  short* M3t = (short*)alloc((size_t)BB * DD * HH * 2);   // 2MB [b][D][H]
  short* dense = xb;  // alias: xb dead after stage 1

  dim3 tb(32, 8);
  cvt_bf16<<<2048, 256, 0, stream>>>(x, xb, BB * SS * DD / 4);
  trW3<<<dim3(HH / 32, DD / 32, 3), tb, 0, stream>>>(Wq, Wk, Wv, WT);
  tr_cvt<<<dim3(HH / 32, SS / 32, 1), tb, 0, stream>>>(Wd, WdT, SS, HH);
  tr_cvt<<<dim3(DD / 32, SS / 32, BB), tb, 0, stream>>>(x, xT, SS, DD);
  bias_cat<<<6, 256, 0, stream>>>(bq, bk, bv, bcat);

  // Stage 1: qkv = x @ [Wq|Wk|Wv] + bias   [8192,1536] K=512
  gemm_bt<128, 1><<<dim3(BB * SS / 128, 1536 / 128, 1), 256, 0, stream>>>(
      xb, WT, qkv, bcat, DD, DD, DD, 3 * HH, 0, 0, 0);
  // k,v transposes
  tr_kv<<<dim3(HH / 32, SS / 32, 8), tb, 0, stream>>>(qkv, kT, vT);
  // Stage 2a+3a: M2[b] = Wd^T @ k[b]; M3t[b] = x^T @ v[b]   [512,512] K=2048
  gemm_dual<<<dim3(4, 4, 8), 256, 0, stream>>>(WdT, kT, M2, xT, vT, M3t);
  // Stage 2b: dense = sigmoid(q @ M2^T + bd)   [2048,512] K=512, batch 4
  gemm_bt<128, 2><<<dim3(SS / 128, HH / 128, BB), 256, 0, stream>>>(
      qkv, M2, dense, bd, HH, 3 * HH, HH, HH, (long)SS * 3 * HH,
      (long)HH * HH, (long)SS * HH);
  // Stage 3b: out = dense @ M3t^T   [2048,512] K=512, batch 4, f32 out
  gemm_bt<128, 3><<<dim3(SS / 128, DD / 128, BB), 256, 0, stream>>>(
      dense, M3t, d_out, nullptr, HH, HH, HH, DD, (long)SS * HH,
      (long)DD * HH, (long)SS * DD);
}

// Round 3
// 100.091 us; speedup vs baseline: 1.9246x; 1.2618x over previous
//
#include <hip/hip_runtime.h>
#include <hip/hip_bf16.h>
#include <stdint.h>

#define BB 4
#define SS 2048
#define DD 512
#define HH 512

typedef __attribute__((ext_vector_type(8))) short short8;
typedef __attribute__((ext_vector_type(4))) float floatx4;

typedef __attribute__((address_space(3))) uint32_t lds_u32_t;
typedef const __attribute__((address_space(1))) uint32_t glb_u32_t;

__device__ __forceinline__ void gload_lds16(const void* g, void* l) {
  __builtin_amdgcn_global_load_lds((glb_u32_t*)g, (lds_u32_t*)l, 16, 0, 0);
}

__device__ __forceinline__ short f2bf(float f) {
  __hip_bfloat16 h = __float2bfloat16(f);
  return __builtin_bit_cast(short, h);
}

__device__ __forceinline__ float bf2f(short s) {
  uint32_t u = ((uint32_t)(uint16_t)s) << 16;
  return __builtin_bit_cast(float, u);
}

// ---------------- GEMM core: C = A * B^T (+bias)(+sigmoid) ----------------
// A: [M,K] bf16 (lda), B: [N,K] bf16 (ldb), C tile at (row0, col0), ldc.
// EPI: 0 = plain -> bf16, 1 = +bias -> bf16, 2 = sigmoid(v+bias) -> bf16,
//      3 = plain -> f32
template <int BM, int EPI>
__device__ __forceinline__ void gemm_core(
    const short* __restrict__ A, const short* __restrict__ Bm,
    void* __restrict__ Cm, long c_base, const float* __restrict__ bias, int K,
    int lda, int ldb, int ldc, long row0, long col0) {
  constexpr int BK = 32;
  constexpr int MF = BM / 32;  // 16x16 m-fragments per wave (per wr half)
  __shared__ short As[BM * BK];
  __shared__ short Bs[128 * BK];

  const short* Ab = A + row0 * lda;
  const short* Bb = Bm + col0 * ldb;

  const int t = threadIdx.x;
  const int lane = t & 63;
  const int wid = t >> 6;
  const int wr = wid >> 1, wc = wid & 1;  // 2x2 wave grid
  const int r16 = lane & 15;
  const int kc = (lane >> 4) * 8;  // k element offset for fragments

  const int st_row = t >> 2;     // staging: row within 64-row slab
  const int st_k = (t & 3) * 8;  // staging: k element offset (16B chunk)

  floatx4 acc[MF][4];
#pragma unroll
  for (int i = 0; i < MF; i++)
#pragma unroll
    for (int j = 0; j < 4; j++) acc[i][j] = (floatx4)0.f;

  for (int k0 = 0; k0 < K; k0 += BK) {
#pragma unroll
    for (int i = 0; i < BM / 64; i++)
      gload_lds16(Ab + (long)(i * 64 + st_row) * lda + k0 + st_k,
                  &As[(i * 64 + st_row) * BK + st_k]);
#pragma unroll
    for (int i = 0; i < 2; i++)
      gload_lds16(Bb + (long)(i * 64 + st_row) * ldb + k0 + st_k,
                  &Bs[(i * 64 + st_row) * BK + st_k]);
    __syncthreads();

    short8 af[MF], bfr[4];
#pragma unroll
    for (int i = 0; i < MF; i++)
      af[i] = *(const short8*)&As[(wr * (BM / 2) + i * 16 + r16) * BK + kc];
#pragma unroll
    for (int j = 0; j < 4; j++)
      bfr[j] = *(const short8*)&Bs[(wc * 64 + j * 16 + r16) * BK + kc];
#pragma unroll
    for (int i = 0; i < MF; i++)
#pragma unroll
      for (int j = 0; j < 4; j++)
        acc[i][j] = __builtin_amdgcn_mfma_f32_16x16x32_bf16(af[i], bfr[j],
                                                            acc[i][j], 0, 0, 0);
    __syncthreads();
  }

  // Epilogue. C/D layout: col = lane&15, row = (lane>>4)*4 + reg.
#pragma unroll
  for (int i = 0; i < MF; i++) {
    const long rbase = row0 + wr * (BM / 2) + i * 16 + (lane >> 4) * 4;
#pragma unroll
    for (int j = 0; j < 4; j++) {
      const long col = col0 + wc * 64 + j * 16 + r16;
      float bv = 0.f;
      if (EPI == 1 || EPI == 2) bv = bias[col];
#pragma unroll
      for (int rg = 0; rg < 4; rg++) {
        float v = acc[i][j][rg];
        if (EPI == 1) v += bv;
        if (EPI == 2) v = 1.f / (1.f + __expf(-(v + bv)));
        const long idx = c_base + (rbase + rg) * ldc + col;
        if (EPI == 3)
          ((float*)Cm)[idx] = v;
        else
          ((__hip_bfloat16*)Cm)[idx] = __float2bfloat16(v);
      }
    }
  }
}

template <int BM, int EPI>
__global__ __launch_bounds__(256) void gemm_bt(
    const short* __restrict__ A, const short* __restrict__ Bm,
    void* __restrict__ Cm, const float* __restrict__ bias, int K, int lda,
    int ldb, int ldc, long sA, long sB, long sC) {
  const int bz = blockIdx.z;
  gemm_core<BM, EPI>(A + bz * sA, Bm + bz * sB, Cm, bz * sC, bias, K, lda, ldb,
                     ldc, (long)blockIdx.x * BM, (long)blockIdx.y * 128);
}

// Split-K dual GEMM. z = tb*4 + split; tb = task*4 + b.
// task 0: M2[b] = WdT @ kT[b]^T ; task 1: M3t[b] = xT[b] @ vT[b]^T
// Each split covers K-chunk [split*512, +512), writes bf16 partial tile.
__global__ __launch_bounds__(256) void gemm_dual_split(
    const short* __restrict__ WdT, const short* __restrict__ kT,
    short* __restrict__ partM2, const short* __restrict__ xT,
    const short* __restrict__ vT, short* __restrict__ partM3) {
  const int bz = blockIdx.z;
  const int tb = bz >> 2, sp = bz & 3;
  const int task = tb >> 2, b = tb & 3;
  const short* A = (task ? xT + (long)b * HH * SS : WdT) + sp * 512;
  const short* B = (task ? vT : kT) + (long)b * HH * SS + sp * 512;
  short* C = (task ? partM3 : partM2) + ((long)(tb & 3) * 4 + sp) * HH * HH;
  gemm_core<128, 0>(A, B, C, 0, nullptr, 512, SS, SS, HH,
                    (long)blockIdx.x * 128, (long)blockIdx.y * 128);
}

// Sum 4 bf16 partials -> bf16. z = 0..7 (task*4+b), 8 elems/thread.
__global__ __launch_bounds__(256) void reduce_part(
    const short* __restrict__ partM2, const short* __restrict__ partM3,
    short* __restrict__ M2, short* __restrict__ M3t) {
  const int z = blockIdx.z;
  const int b = z & 3;
  const short* src = (z < 4 ? partM2 : partM3) + (long)b * 4 * HH * HH;
  short* dst = (z < 4 ? M2 : M3t) + (long)b * HH * HH;
  const long i = ((long)blockIdx.x * 256 + threadIdx.x) * 8;
  float s[8];
#pragma unroll
  for (int j = 0; j < 8; j++) s[j] = 0.f;
#pragma unroll
  for (int sp = 0; sp < 4; sp++) {
    short8 v = *(const short8*)&src[(long)sp * HH * HH + i];
#pragma unroll
    for (int j = 0; j < 8; j++) s[j] += bf2f(v[j]);
  }
  short o[8];
#pragma unroll
  for (int j = 0; j < 8; j++) o[j] = f2bf(s[j]);
  *(short8*)&dst[i] = *(short8*)o;
}

// ---------------- conversions ----------------
// x f32 [b][S][D] -> xb bf16 (same layout) AND xT bf16 [b][D][S]
__global__ void tr_x(const float* __restrict__ x, short* __restrict__ xb,
                     short* __restrict__ xT) {
  __shared__ float tile[32][33];
  const long b = blockIdx.z;
  const float* in = x + b * SS * DD;
  const int c0 = blockIdx.x * 32, r0 = blockIdx.y * 32;  // c over D, r over S
  const int tx = threadIdx.x, ty = threadIdx.y;          // (32, 8)
#pragma unroll
  for (int i = 0; i < 32; i += 8) {
    float v = in[(long)(r0 + ty + i) * DD + c0 + tx];
    tile[ty + i][tx] = v;
    xb[(b * SS + r0 + ty + i) * DD + c0 + tx] = f2bf(v);
  }
  __syncthreads();
#pragma unroll
  for (int i = 0; i < 32; i += 8)
    xT[(b * DD + c0 + ty + i) * SS + r0 + tx] = f2bf(tile[tx][ty + i]);
}

// in: f32 [R][C], out: bf16 [C][R]
__global__ void tr_cvt(const float* __restrict__ in, short* __restrict__ out,
                       int R, int C) {
  __shared__ float tile[32][33];
  const int c0 = blockIdx.x * 32, r0 = blockIdx.y * 32;
  const int tx = threadIdx.x, ty = threadIdx.y;  // (32, 8)
#pragma unroll
  for (int i = 0; i < 32; i += 8)
    tile[ty + i][tx] = in[(long)(r0 + ty + i) * C + c0 + tx];
  __syncthreads();
#pragma unroll
  for (int i = 0; i < 32; i += 8)
    out[(long)(c0 + ty + i) * R + r0 + tx] = f2bf(tile[tx][ty + i]);
}

// Wq|Wk|Wv [512][512] f32 -> WT [3*512][512] bf16 transposed, z selects W
__global__ void trW3(const float* __restrict__ Wq, const float* __restrict__ Wk,
                     const float* __restrict__ Wv, short* __restrict__ WT) {
  __shared__ float tile[32][33];
  const int z = blockIdx.z;
  const float* in = z == 0 ? Wq : (z == 1 ? Wk : Wv);
  short* out = WT + (long)z * HH * DD;
  const int c0 = blockIdx.x * 32, r0 = blockIdx.y * 32;
  const int tx = threadIdx.x, ty = threadIdx.y;
#pragma unroll
  for (int i = 0; i < 32; i += 8)
    tile[ty + i][tx] = in[(long)(r0 + ty + i) * HH + c0 + tx];
  __syncthreads();
#pragma unroll
  for (int i = 0; i < 32; i += 8)
    out[(long)(c0 + ty + i) * DD + r0 + tx] = f2bf(tile[tx][ty + i]);
}

// k,v slices of qkv -> kT,vT [512][2048] bf16 per batch. z: (which<<2)|b
__global__ void tr_kv(const short* __restrict__ qkv, short* __restrict__ kT,
                      short* __restrict__ vT) {
  __shared__ short tile[32][34];
  const int z = blockIdx.z;
  const int which = z >> 2, b = z & 3;
  const short* in = qkv + (long)b * SS * (3 * HH) + (1 + which) * HH;
  short* out = (which ? vT : kT) + (long)b * HH * SS;
  const int c0 = blockIdx.x * 32, r0 = blockIdx.y * 32;
  const int tx = threadIdx.x, ty = threadIdx.y;  // (32, 8)
#pragma unroll
  for (int i = 0; i < 32; i += 8)
    tile[ty + i][tx] = in[(long)(r0 + ty + i) * (3 * HH) + c0 + tx];
  __syncthreads();
#pragma unroll
  for (int i = 0; i < 32; i += 8)
    out[(long)(c0 + ty + i) * SS + r0 + tx] = tile[tx][ty + i];
}

__global__ void bias_cat(const float* __restrict__ bq,
                         const float* __restrict__ bk,
                         const float* __restrict__ bv,
                         float* __restrict__ bcat) {
  int i = blockIdx.x * blockDim.x + threadIdx.x;
  if (i < 512)
    bcat[i] = bq[i];
  else if (i < 1024)
    bcat[i] = bk[i - 512];
  else if (i < 1536)
    bcat[i] = bv[i - 1024];
}

extern "C" void kernel_launch(void* const* d_in, const int* in_sizes, int n_in,
                              void* d_out, int out_size, void* d_ws,
                              size_t ws_size, hipStream_t stream) {
  (void)in_sizes;
  (void)n_in;
  (void)out_size;
  (void)ws_size;
  const float* x = (const float*)d_in[0];
  const float* Wq = (const float*)d_in[1];
  const float* bq = (const float*)d_in[2];
  const float* Wk = (const float*)d_in[3];
  const float* bk = (const float*)d_in[4];
  const float* Wv = (const float*)d_in[5];
  const float* bv = (const float*)d_in[6];
  const float* Wd = (const float*)d_in[7];
  const float* bd = (const float*)d_in[8];

  char* w = (char*)d_ws;
  auto alloc = [&](size_t bytes) {
    char* p = w;
    w += (bytes + 255) & ~(size_t)255;
    return p;
  };
  short* xb = (short*)alloc((size_t)BB * SS * DD * 2);     // 8MB
  short* xT = (short*)alloc((size_t)BB * DD * SS * 2);     // 8MB [b][D][S]
  short* WT = (short*)alloc((size_t)3 * HH * DD * 2);      // 1.5MB
  short* WdT = (short*)alloc((size_t)HH * SS * 2);         // 2MB [512][2048]
  float* bcat = (float*)alloc((size_t)3 * HH * 4);
  short* qkv = (short*)alloc((size_t)BB * SS * 3 * HH * 2);  // 24MB
  short* kT = (short*)alloc((size_t)BB * HH * SS * 2);     // 8MB [b][H][S]
  short* vT = (short*)alloc((size_t)BB * HH * SS * 2);     // 8MB [b][H][S]
  short* M2 = (short*)alloc((size_t)BB * HH * HH * 2);     // 2MB
  short* M3t = (short*)alloc((size_t)BB * DD * HH * 2);    // 2MB
  short* partM3 = (short*)alloc((size_t)BB * 4 * HH * HH * 2);  // 8MB fresh
  // overlays (lifetimes disjoint): partM2 and dense reuse the xb region
  short* partM2 = xb;  // 8MB: written by dual (xb dead), read by reduce
  short* dense = xb;   // written by stage 2b (after reduce read)

  dim3 tb(32, 8);
  tr_x<<<dim3(DD / 32, SS / 32, BB), tb, 0, stream>>>(x, xb, xT);
  trW3<<<dim3(HH / 32, DD / 32, 3), tb, 0, stream>>>(Wq, Wk, Wv, WT);
  tr_cvt<<<dim3(HH / 32, SS / 32, 1), tb, 0, stream>>>(Wd, WdT, SS, HH);
  bias_cat<<<6, 256, 0, stream>>>(bq, bk, bv, bcat);

  // Stage 1: qkv = x @ [Wq|Wk|Wv] + bias   [8192,1536] K=512
  gemm_bt<128, 1><<<dim3(BB * SS / 128, 1536 / 128, 1), 256, 0, stream>>>(
      xb, WT, qkv, bcat, DD, DD, DD, 3 * HH, 0, 0, 0);
  // k,v transposes
  tr_kv<<<dim3(HH / 32, SS / 32, 8), tb, 0, stream>>>(qkv, kT, vT);
  // Stage 2a+3a split-K: partials for M2[b]=Wd^T@k[b], M3t[b]=x^T@v[b]
  gemm_dual_split<<<dim3(4, 4, 32), 256, 0, stream>>>(WdT, kT, partM2, xT, vT,
                                                      partM3);
  reduce_part<<<dim3(128, 1, 8), 256, 0, stream>>>(partM2, partM3, M2, M3t);
  // Stage 2b: dense = sigmoid(q @ M2^T + bd)   [2048,512] K=512, batch 4
  gemm_bt<64, 2><<<dim3(SS / 64, HH / 128, BB), 256, 0, stream>>>(
      qkv, M2, dense, bd, HH, 3 * HH, HH, HH, (long)SS * 3 * HH, (long)HH * HH,
      (long)SS * HH);
  // Stage 3b: out = dense @ M3t^T   [2048,512] K=512, batch 4, f32 out
  gemm_bt<64, 3><<<dim3(SS / 64, DD / 128, BB), 256, 0, stream>>>(
      dense, M3t, d_out, nullptr, HH, HH, HH, DD, (long)SS * HH, (long)DD * HH,
      (long)SS * DD);
}

// Round 4
// 90.721 us; speedup vs baseline: 2.1234x; 1.1033x over previous
//
#include <hip/hip_runtime.h>
#include <hip/hip_bf16.h>
#include <stdint.h>

#define BB 4
#define SS 2048
#define DD 512
#define HH 512

typedef __attribute__((ext_vector_type(8))) short short8;
typedef __attribute__((ext_vector_type(4))) float floatx4;

typedef __attribute__((address_space(3))) uint32_t lds_u32_t;
typedef const __attribute__((address_space(1))) uint32_t glb_u32_t;

__device__ __forceinline__ void gload_lds16(const void* g, void* l) {
  __builtin_amdgcn_global_load_lds((glb_u32_t*)g, (lds_u32_t*)l, 16, 0, 0);
}

__device__ __forceinline__ short f2bf(float f) {
  __hip_bfloat16 h = __float2bfloat16(f);
  return __builtin_bit_cast(short, h);
}

__device__ __forceinline__ float bf2f(short s) {
  uint32_t u = ((uint32_t)(uint16_t)s) << 16;
  return __builtin_bit_cast(float, u);
}

// ---------------- GEMM main loop: acc += A-tile * B-tile^T ----------------
// A: [M,K] bf16 (lda), B: [N,K] bf16 (ldb). 4 waves in 2x2 grid, BN=128.
template <int BM>
__device__ __forceinline__ void gemm_mainloop(const short* __restrict__ Ab,
                                              const short* __restrict__ Bb,
                                              int lda, int ldb, int K,
                                              floatx4 (&acc)[BM / 32][4]) {
  constexpr int BK = 32;
  constexpr int MF = BM / 32;
  __shared__ short As[BM * BK];
  __shared__ short Bs[128 * BK];

  const int t = threadIdx.x;
  const int lane = t & 63;
  const int wid = t >> 6;
  const int wr = wid >> 1, wc = wid & 1;
  const int r16 = lane & 15;
  const int kc = (lane >> 4) * 8;

  const int st_row = t >> 2;     // staging: row within 64-row slab
  const int st_k = (t & 3) * 8;  // staging: k element offset (16B chunk)

#pragma unroll
  for (int i = 0; i < MF; i++)
#pragma unroll
    for (int j = 0; j < 4; j++) acc[i][j] = (floatx4)0.f;

  for (int k0 = 0; k0 < K; k0 += BK) {
#pragma unroll
    for (int i = 0; i < BM / 64; i++)
      gload_lds16(Ab + (long)(i * 64 + st_row) * lda + k0 + st_k,
                  &As[(i * 64 + st_row) * BK + st_k]);
#pragma unroll
    for (int i = 0; i < 2; i++)
      gload_lds16(Bb + (long)(i * 64 + st_row) * ldb + k0 + st_k,
                  &Bs[(i * 64 + st_row) * BK + st_k]);
    __syncthreads();

    short8 af[MF], bfr[4];
#pragma unroll
    for (int i = 0; i < MF; i++)
      af[i] = *(const short8*)&As[(wr * (BM / 2) + i * 16 + r16) * BK + kc];
#pragma unroll
    for (int j = 0; j < 4; j++)
      bfr[j] = *(const short8*)&Bs[(wc * 64 + j * 16 + r16) * BK + kc];
#pragma unroll
    for (int i = 0; i < MF; i++)
#pragma unroll
      for (int j = 0; j < 4; j++)
        acc[i][j] = __builtin_amdgcn_mfma_f32_16x16x32_bf16(af[i], bfr[j],
                                                            acc[i][j], 0, 0, 0);
    __syncthreads();
  }
}

// Standard row-major epilogue. C/D layout: col = lane&15, row = (lane>>4)*4+reg.
// EPI: 0 plain->bf16, 2 sigmoid(v+bias)->bf16, 3 plain->f32
template <int BM, int EPI>
__device__ __forceinline__ void epilogue_std(floatx4 (&acc)[BM / 32][4],
                                             void* __restrict__ Cm, long c_base,
                                             const float* __restrict__ bias,
                                             int ldc, long row0, long col0) {
  const int lane = threadIdx.x & 63;
  const int wid = threadIdx.x >> 6;
  const int wr = wid >> 1, wc = wid & 1;
  const int r16 = lane & 15;
#pragma unroll
  for (int i = 0; i < BM / 32; i++) {
    const long rbase = row0 + wr * (BM / 2) + i * 16 + (lane >> 4) * 4;
#pragma unroll
    for (int j = 0; j < 4; j++) {
      const long col = col0 + wc * 64 + j * 16 + r16;
      float bv = 0.f;
      if (EPI == 2) bv = bias[col];
#pragma unroll
      for (int rg = 0; rg < 4; rg++) {
        float v = acc[i][j][rg];
        if (EPI == 2) v = 1.f / (1.f + __expf(-(v + bv)));
        const long idx = c_base + (rbase + rg) * ldc + col;
        if (EPI == 3)
          ((float*)Cm)[idx] = v;
        else
          ((__hip_bfloat16*)Cm)[idx] = __float2bfloat16(v);
      }
    }
  }
}

template <int BM, int EPI>
__global__ __launch_bounds__(256) void gemm_bt(
    const short* __restrict__ A, const short* __restrict__ Bm,
    void* __restrict__ Cm, const float* __restrict__ bias, int K, int lda,
    int ldb, int ldc, long sA, long sB, long sC) {
  const int bz = blockIdx.z;
  floatx4 acc[BM / 32][4];
  const long row0 = (long)blockIdx.x * BM, col0 = (long)blockIdx.y * 128;
  gemm_mainloop<BM>(A + bz * sA + row0 * lda, Bm + bz * sB + col0 * ldb, lda,
                    ldb, K, acc);
  epilogue_std<BM, EPI>(acc, Cm, bz * sC, bias, ldc, row0, col0);
}

// Stage 1: qkv projection with direct-layout outputs.
// y 0..3 -> q [b][S][H] row-major; y 4..7 -> kT [b][H][S]; y 8..11 -> vT.
__global__ __launch_bounds__(256) void gemm_qkv(
    const short* __restrict__ xb, const short* __restrict__ WT,
    const float* __restrict__ bcat, short* __restrict__ q,
    short* __restrict__ kT, short* __restrict__ vT) {
  floatx4 acc[4][4];
  const long row0 = (long)blockIdx.x * 128;  // global row over B*S
  const int y = blockIdx.y;
  gemm_mainloop<128>(xb + row0 * DD, WT + (long)y * 128 * DD, DD, DD, DD, acc);

  const int lane = threadIdx.x & 63;
  const int wid = threadIdx.x >> 6;
  const int wr = wid >> 1, wc = wid & 1;
  const int r16 = lane & 15;
  const int hi4 = (lane >> 4) * 4;
  const int mode = y >> 2;
  const int b = (int)(row0 >> 11);
  const int sblk = (int)(row0 & 2047);
  short* tp = (mode == 1) ? kT : vT;
#pragma unroll
  for (int i = 0; i < 4; i++) {
    const int s0 = sblk + wr * 64 + i * 16 + hi4;
#pragma unroll
    for (int j = 0; j < 4; j++) {
      const int colg = y * 128 + wc * 64 + j * 16 + r16;
      const float bv = bcat[colg];
      short o[4];
#pragma unroll
      for (int rg = 0; rg < 4; rg++) o[rg] = f2bf(acc[i][j][rg] + bv);
      if (mode == 0) {
#pragma unroll
        for (int rg = 0; rg < 4; rg++)
          q[((long)b * SS + s0 + rg) * HH + colg] = o[rg];
      } else {
        const int cl = colg - mode * 512;
        *(uint64_t*)&tp[((long)b * HH + cl) * SS + s0] = *(uint64_t*)o;
      }
    }
  }
}

// Split-K dual GEMM. z = tb*4 + split; tb = task*4 + b.
// task 0: M2[b] = WdT @ kT[b]^T ; task 1: M3t[b] = xT[b] @ vT[b]^T
__global__ __launch_bounds__(256) void gemm_dual_split(
    const short* __restrict__ WdT, const short* __restrict__ kT,
    short* __restrict__ partM2, const short* __restrict__ xT,
    const short* __restrict__ vT, short* __restrict__ partM3) {
  const int bz = blockIdx.z;
  const int tb = bz >> 2, sp = bz & 3;
  const int task = tb >> 2, b = tb & 3;
  const short* A = (task ? xT + (long)b * HH * SS : WdT) + sp * 512;
  const short* B = (task ? vT : kT) + (long)b * HH * SS + sp * 512;
  short* C = (task ? partM3 : partM2) + ((long)(tb & 3) * 4 + sp) * HH * HH;
  floatx4 acc[2][4];
  const long row0 = (long)blockIdx.x * 64, col0 = (long)blockIdx.y * 128;
  gemm_mainloop<64>(A + row0 * SS, B + col0 * SS, SS, SS, 512, acc);
  epilogue_std<64, 0>(acc, C, 0, nullptr, HH, row0, col0);
}

// Sum 4 bf16 partials -> bf16. z = 0..7 (task*4+b), 8 elems/thread.
__global__ __launch_bounds__(256) void reduce_part(
    const short* __restrict__ partM2, const short* __restrict__ partM3,
    short* __restrict__ M2, short* __restrict__ M3t) {
  const int z = blockIdx.z;
  const int b = z & 3;
  const short* src = (z < 4 ? partM2 : partM3) + (long)b * 4 * HH * HH;
  short* dst = (z < 4 ? M2 : M3t) + (long)b * HH * HH;
  const long i = ((long)blockIdx.x * 256 + threadIdx.x) * 8;
  float s[8];
#pragma unroll
  for (int j = 0; j < 8; j++) s[j] = 0.f;
#pragma unroll
  for (int sp = 0; sp < 4; sp++) {
    short8 v = *(const short8*)&src[(long)sp * HH * HH + i];
#pragma unroll
    for (int j = 0; j < 8; j++) s[j] += bf2f(v[j]);
  }
  short o[8];
#pragma unroll
  for (int j = 0; j < 8; j++) o[j] = f2bf(s[j]);
  *(short8*)&dst[i] = *(short8*)o;
}

// ---------------- conversions ----------------
// x f32 [b][S][D] -> xb bf16 (same layout) AND xT bf16 [b][D][S]
__global__ void tr_x(const float* __restrict__ x, short* __restrict__ xb,
                     short* __restrict__ xT) {
  __shared__ float tile[32][33];
  const long b = blockIdx.z;
  const float* in = x + b * SS * DD;
  const int c0 = blockIdx.x * 32, r0 = blockIdx.y * 32;  // c over D, r over S
  const int tx = threadIdx.x, ty = threadIdx.y;          // (32, 8)
#pragma unroll
  for (int i = 0; i < 32; i += 8) {
    float v = in[(long)(r0 + ty + i) * DD + c0 + tx];
    tile[ty + i][tx] = v;
    xb[(b * SS + r0 + ty + i) * DD + c0 + tx] = f2bf(v);
  }
  __syncthreads();
#pragma unroll
  for (int i = 0; i < 32; i += 8)
    xT[(b * DD + c0 + ty + i) * SS + r0 + tx] = f2bf(tile[tx][ty + i]);
}

// All weight prep in one kernel. grid (16, 64, 4), block (32,8).
// z 0..2, y<16: W{q,k,v} [512][512] -> WT[z] transposed bf16
// z 0,  y 16..21: bcat = [bq|bk|bv]
// z 3: Wd [2048][512] -> WdT [512][2048] bf16
__global__ void prep_w(const float* __restrict__ Wq,
                       const float* __restrict__ Wk,
                       const float* __restrict__ Wv,
                       const float* __restrict__ Wd,
                       const float* __restrict__ bq,
                       const float* __restrict__ bk,
                       const float* __restrict__ bv, short* __restrict__ WT,
                       short* __restrict__ WdT, float* __restrict__ bcat) {
  __shared__ float tile[32][33];
  const int z = blockIdx.z, yb = blockIdx.y;
  const int tx = threadIdx.x, ty = threadIdx.y;
  if (z < 3) {
    if (yb < 16) {
      const float* in = z == 0 ? Wq : (z == 1 ? Wk : Wv);
      short* out = WT + (long)z * HH * DD;
      const int c0 = blockIdx.x * 32, r0 = yb * 32;
#pragma unroll
      for (int i = 0; i < 32; i += 8)
        tile[ty + i][tx] = in[(long)(r0 + ty + i) * HH + c0 + tx];
      __syncthreads();
#pragma unroll
      for (int i = 0; i < 32; i += 8)
        out[(long)(c0 + ty + i) * DD + r0 + tx] = f2bf(tile[tx][ty + i]);
    } else if (z == 0 && yb < 22 && blockIdx.x == 0) {
      const int i = (yb - 16) * 256 + ty * 32 + tx;
      bcat[i] = i < 512 ? bq[i] : (i < 1024 ? bk[i - 512] : bv[i - 1024]);
    }
  } else {
    const int c0 = blockIdx.x * 32, r0 = yb * 32;  // c over H, r over S
#pragma unroll
    for (int i = 0; i < 32; i += 8)
      tile[ty + i][tx] = Wd[(long)(r0 + ty + i) * HH + c0 + tx];
    __syncthreads();
#pragma unroll
    for (int i = 0; i < 32; i += 8)
      WdT[(long)(c0 + ty + i) * SS + r0 + tx] = f2bf(tile[tx][ty + i]);
  }
}

extern "C" void kernel_launch(void* const* d_in, const int* in_sizes, int n_in,
                              void* d_out, int out_size, void* d_ws,
                              size_t ws_size, hipStream_t stream) {
  (void)in_sizes;
  (void)n_in;
  (void)out_size;
  (void)ws_size;
  const float* x = (const float*)d_in[0];
  const float* Wq = (const float*)d_in[1];
  const float* bq = (const float*)d_in[2];
  const float* Wk = (const float*)d_in[3];
  const float* bk = (const float*)d_in[4];
  const float* Wv = (const float*)d_in[5];
  const float* bv = (const float*)d_in[6];
  const float* Wd = (const float*)d_in[7];
  const float* bd = (const float*)d_in[8];

  char* w = (char*)d_ws;
  auto alloc = [&](size_t bytes) {
    char* p = w;
    w += (bytes + 255) & ~(size_t)255;
    return p;
  };
  short* xb = (short*)alloc((size_t)BB * SS * DD * 2);        // 8MB
  short* xT = (short*)alloc((size_t)BB * DD * SS * 2);        // 8MB [b][D][S]
  short* WT = (short*)alloc((size_t)3 * HH * DD * 2);         // 1.5MB
  short* WdT = (short*)alloc((size_t)HH * SS * 2);            // 2MB
  float* bcat = (float*)alloc((size_t)3 * HH * 4);
  short* q = (short*)alloc((size_t)BB * SS * HH * 2);         // 8MB [b][S][H]
  short* kT = (short*)alloc((size_t)BB * HH * SS * 2);        // 8MB [b][H][S]
  short* vT = (short*)alloc((size_t)BB * HH * SS * 2);        // 8MB [b][H][S]
  short* partM2 = (short*)alloc((size_t)BB * 4 * HH * HH * 2);  // 8MB
  short* partM3 = (short*)alloc((size_t)BB * 4 * HH * HH * 2);  // 8MB
  short* M2 = (short*)alloc((size_t)BB * HH * HH * 2);        // 2MB
  short* M3t = (short*)alloc((size_t)BB * DD * HH * 2);       // 2MB
  short* dense = (short*)alloc((size_t)BB * SS * HH * 2);     // 8MB

  dim3 tb(32, 8);
  tr_x<<<dim3(DD / 32, SS / 32, BB), tb, 0, stream>>>(x, xb, xT);
  prep_w<<<dim3(16, 64, 4), tb, 0, stream>>>(Wq, Wk, Wv, Wd, bq, bk, bv, WT,
                                             WdT, bcat);

  // Stage 1: q/kT/vT = x @ [Wq|Wk|Wv] + bias, direct layouts
  gemm_qkv<<<dim3(BB * SS / 128, 12, 1), 256, 0, stream>>>(xb, WT, bcat, q, kT,
                                                           vT);
  // Stage 2a+3a split-K: partials for M2[b]=Wd^T@k[b], M3t[b]=x^T@v[b]
  gemm_dual_split<<<dim3(8, 4, 32), 256, 0, stream>>>(WdT, kT, partM2, xT, vT,
                                                      partM3);
  reduce_part<<<dim3(128, 1, 8), 256, 0, stream>>>(partM2, partM3, M2, M3t);
  // Stage 2b: dense = sigmoid(q @ M2^T + bd)   [2048,512] K=512, batch 4
  gemm_bt<64, 2><<<dim3(SS / 64, HH / 128, BB), 256, 0, stream>>>(
      q, M2, dense, bd, HH, HH, HH, HH, (long)SS * HH, (long)HH * HH,
      (long)SS * HH);
  // Stage 3b: out = dense @ M3t^T   [2048,512] K=512, batch 4, f32 out
  gemm_bt<64, 3><<<dim3(SS / 64, DD / 128, BB), 256, 0, stream>>>(
      dense, M3t, d_out, nullptr, HH, HH, HH, DD, (long)SS * HH, (long)DD * HH,
      (long)SS * DD);
}

// Round 5
// 81.947 us; speedup vs baseline: 2.3507x; 1.1071x over previous
//
#include <hip/hip_runtime.h>
#include <hip/hip_bf16.h>
#include <stdint.h>

#define BB 4
#define SS 2048
#define DD 512
#define HH 512

typedef __attribute__((ext_vector_type(8))) short short8;
typedef __attribute__((ext_vector_type(4))) float floatx4;

typedef __attribute__((address_space(3))) uint32_t lds_u32_t;
typedef const __attribute__((address_space(1))) uint32_t glb_u32_t;

__device__ __forceinline__ void gload_lds16(const void* g, void* l) {
  __builtin_amdgcn_global_load_lds((glb_u32_t*)g, (lds_u32_t*)l, 16, 0, 0);
}

__device__ __forceinline__ short f2bf(float f) {
  __hip_bfloat16 h = __float2bfloat16(f);
  return __builtin_bit_cast(short, h);
}

__device__ __forceinline__ float bf2f(short s) {
  uint32_t u = ((uint32_t)(uint16_t)s) << 16;
  return __builtin_bit_cast(float, u);
}

// ---------------- GEMM main loop: acc += A-tile * B-tile^T ----------------
// A: [M,K] bf16 (lda), B: [N,K] bf16 (ldb). 4 waves in 2x2 grid, BN=128.
// BK=64. LDS rows are 8 x 16B chunks; chunk c of row r holds global chunk
// c ^ (r&7) (source-side pre-swizzle; ds_read applies the same XOR).
template <int BM>
__device__ __forceinline__ void gemm_mainloop(const short* __restrict__ Ab,
                                              const short* __restrict__ Bb,
                                              int lda, int ldb, int K,
                                              floatx4 (&acc)[BM / 32][4]) {
  constexpr int BK = 64;
  constexpr int MF = BM / 32;
  __shared__ short As[BM * BK];
  __shared__ short Bs[128 * BK];

  const int t = threadIdx.x;
  const int lane = t & 63;
  const int wid = t >> 6;
  const int wr = wid >> 1, wc = wid & 1;
  const int r16 = lane & 15;
  const int hi = lane >> 4;  // 0..3

  const int srow = t >> 3;    // staging row within a 32-row slab
  const int schunk = t & 7;   // LDS 16B slot index within the row

#pragma unroll
  for (int i = 0; i < MF; i++)
#pragma unroll
    for (int j = 0; j < 4; j++) acc[i][j] = (floatx4)0.f;

  for (int k0 = 0; k0 < K; k0 += BK) {
#pragma unroll
    for (int s = 0; s < BM / 32; s++) {
      const int row = s * 32 + srow;
      const int g = schunk ^ (row & 7);  // global chunk for this LDS slot
      gload_lds16(Ab + (long)row * lda + k0 + g * 8,
                  &As[row * BK + schunk * 8]);
    }
#pragma unroll
    for (int s = 0; s < 4; s++) {
      const int row = s * 32 + srow;
      const int g = schunk ^ (row & 7);
      gload_lds16(Bb + (long)row * ldb + k0 + g * 8,
                  &Bs[row * BK + schunk * 8]);
    }
    __syncthreads();

    short8 af[MF][2], bfr[4][2];
#pragma unroll
    for (int i = 0; i < MF; i++) {
      const int row = wr * (BM / 2) + i * 16 + r16;
      const int x7 = row & 7;
      af[i][0] = *(const short8*)&As[row * BK + (hi ^ x7) * 8];
      af[i][1] = *(const short8*)&As[row * BK + ((hi + 4) ^ x7) * 8];
    }
#pragma unroll
    for (int j = 0; j < 4; j++) {
      const int row = wc * 64 + j * 16 + r16;
      const int x7 = row & 7;
      bfr[j][0] = *(const short8*)&Bs[row * BK + (hi ^ x7) * 8];
      bfr[j][1] = *(const short8*)&Bs[row * BK + ((hi + 4) ^ x7) * 8];
    }
#pragma unroll
    for (int i = 0; i < MF; i++)
#pragma unroll
      for (int j = 0; j < 4; j++) {
        acc[i][j] = __builtin_amdgcn_mfma_f32_16x16x32_bf16(
            af[i][0], bfr[j][0], acc[i][j], 0, 0, 0);
        acc[i][j] = __builtin_amdgcn_mfma_f32_16x16x32_bf16(
            af[i][1], bfr[j][1], acc[i][j], 0, 0, 0);
      }
    __syncthreads();
  }
}

// Standard row-major epilogue. C/D layout: col = lane&15, row = (lane>>4)*4+reg.
// EPI: 0 plain->bf16, 2 sigmoid(v+bias)->bf16, 3 plain->f32
template <int BM, int EPI>
__device__ __forceinline__ void epilogue_std(floatx4 (&acc)[BM / 32][4],
                                             void* __restrict__ Cm, long c_base,
                                             const float* __restrict__ bias,
                                             int ldc, long row0, long col0) {
  const int lane = threadIdx.x & 63;
  const int wid = threadIdx.x >> 6;
  const int wr = wid >> 1, wc = wid & 1;
  const int r16 = lane & 15;
#pragma unroll
  for (int i = 0; i < BM / 32; i++) {
    const long rbase = row0 + wr * (BM / 2) + i * 16 + (lane >> 4) * 4;
#pragma unroll
    for (int j = 0; j < 4; j++) {
      const long col = col0 + wc * 64 + j * 16 + r16;
      float bv = 0.f;
      if (EPI == 2) bv = bias[col];
#pragma unroll
      for (int rg = 0; rg < 4; rg++) {
        float v = acc[i][j][rg];
        if (EPI == 2) v = 1.f / (1.f + __expf(-(v + bv)));
        const long idx = c_base + (rbase + rg) * ldc + col;
        if (EPI == 3)
          ((float*)Cm)[idx] = v;
        else
          ((__hip_bfloat16*)Cm)[idx] = __float2bfloat16(v);
      }
    }
  }
}

template <int BM, int EPI>
__global__ __launch_bounds__(256) void gemm_bt(
    const short* __restrict__ A, const short* __restrict__ Bm,
    void* __restrict__ Cm, const float* __restrict__ bias, int K, int lda,
    int ldb, int ldc, long sA, long sB, long sC) {
  const int bz = blockIdx.z;
  floatx4 acc[BM / 32][4];
  const long row0 = (long)blockIdx.x * BM, col0 = (long)blockIdx.y * 128;
  gemm_mainloop<BM>(A + bz * sA + row0 * lda, Bm + bz * sB + col0 * ldb, lda,
                    ldb, K, acc);
  epilogue_std<BM, EPI>(acc, Cm, bz * sC, bias, ldc, row0, col0);
}

// Stage 1: qkv projection with direct-layout outputs.
// y 0..3 -> q [b][S][H] row-major; y 4..7 -> kT [b][H][S]; y 8..11 -> vT.
__global__ __launch_bounds__(256) void gemm_qkv(
    const short* __restrict__ xb, const short* __restrict__ WT,
    const float* __restrict__ bcat, short* __restrict__ q,
    short* __restrict__ kT, short* __restrict__ vT) {
  floatx4 acc[4][4];
  const long row0 = (long)blockIdx.x * 128;  // global row over B*S
  const int y = blockIdx.y;
  gemm_mainloop<128>(xb + row0 * DD, WT + (long)y * 128 * DD, DD, DD, DD, acc);

  const int lane = threadIdx.x & 63;
  const int wid = threadIdx.x >> 6;
  const int wr = wid >> 1, wc = wid & 1;
  const int r16 = lane & 15;
  const int hi4 = (lane >> 4) * 4;
  const int mode = y >> 2;
  const int b = (int)(row0 >> 11);
  const int sblk = (int)(row0 & 2047);
  short* tp = (mode == 1) ? kT : vT;
#pragma unroll
  for (int i = 0; i < 4; i++) {
    const int s0 = sblk + wr * 64 + i * 16 + hi4;
#pragma unroll
    for (int j = 0; j < 4; j++) {
      const int colg = y * 128 + wc * 64 + j * 16 + r16;
      const float bv = bcat[colg];
      short o[4];
#pragma unroll
      for (int rg = 0; rg < 4; rg++) o[rg] = f2bf(acc[i][j][rg] + bv);
      if (mode == 0) {
#pragma unroll
        for (int rg = 0; rg < 4; rg++)
          q[((long)b * SS + s0 + rg) * HH + colg] = o[rg];
      } else {
        const int cl = colg - mode * 512;
        *(uint64_t*)&tp[((long)b * HH + cl) * SS + s0] = *(uint64_t*)o;
      }
    }
  }
}

// Split-K dual GEMM. z = tb*4 + split; tb = task*4 + b.
// task 0: M2[b] = WdT @ kT[b]^T ; task 1: M3t[b] = xT[b] @ vT[b]^T
__global__ __launch_bounds__(256) void gemm_dual_split(
    const short* __restrict__ WdT, const short* __restrict__ kT,
    short* __restrict__ partM2, const short* __restrict__ xT,
    const short* __restrict__ vT, short* __restrict__ partM3) {
  const int bz = blockIdx.z;
  const int tb = bz >> 2, sp = bz & 3;
  const int task = tb >> 2, b = tb & 3;
  const short* A = (task ? xT + (long)b * HH * SS : WdT) + sp * 512;
  const short* B = (task ? vT : kT) + (long)b * HH * SS + sp * 512;
  short* C = (task ? partM3 : partM2) + ((long)(tb & 3) * 4 + sp) * HH * HH;
  floatx4 acc[2][4];
  const long row0 = (long)blockIdx.x * 64, col0 = (long)blockIdx.y * 128;
  gemm_mainloop<64>(A + row0 * SS, B + col0 * SS, SS, SS, 512, acc);
  epilogue_std<64, 0>(acc, C, 0, nullptr, HH, row0, col0);
}

// Sum 4 bf16 partials -> bf16. z = 0..7 (task*4+b), 8 elems/thread.
__global__ __launch_bounds__(256) void reduce_part(
    const short* __restrict__ partM2, const short* __restrict__ partM3,
    short* __restrict__ M2, short* __restrict__ M3t) {
  const int z = blockIdx.z;
  const int b = z & 3;
  const short* src = (z < 4 ? partM2 : partM3) + (long)b * 4 * HH * HH;
  short* dst = (z < 4 ? M2 : M3t) + (long)b * HH * HH;
  const long i = ((long)blockIdx.x * 256 + threadIdx.x) * 8;
  float s[8];
#pragma unroll
  for (int j = 0; j < 8; j++) s[j] = 0.f;
#pragma unroll
  for (int sp = 0; sp < 4; sp++) {
    short8 v = *(const short8*)&src[(long)sp * HH * HH + i];
#pragma unroll
    for (int j = 0; j < 8; j++) s[j] += bf2f(v[j]);
  }
  short o[8];
#pragma unroll
  for (int j = 0; j < 8; j++) o[j] = f2bf(s[j]);
  *(short8*)&dst[i] = *(short8*)o;
}

// ---------------- fused prep: x conversions + all weight prep ----------------
// grid (16, 64, 8), block (32,8).
// z 0..3: batch z of x: f32 [S][D] -> xb bf16 same layout AND xT bf16 [D][S]
// z 4..6: W{q,k,v} [512][512] -> WT[z-4] transposed bf16 (y<16)
//         z==4, y 16..21, x==0: bcat = [bq|bk|bv]
// z 7:    Wd [2048][512] -> WdT [512][2048] bf16
__global__ void prep(const float* __restrict__ x, const float* __restrict__ Wq,
                     const float* __restrict__ Wk, const float* __restrict__ Wv,
                     const float* __restrict__ Wd, const float* __restrict__ bq,
                     const float* __restrict__ bk, const float* __restrict__ bv,
                     short* __restrict__ xb, short* __restrict__ xT,
                     short* __restrict__ WT, short* __restrict__ WdT,
                     float* __restrict__ bcat) {
  __shared__ float tile[32][33];
  const int z = blockIdx.z, yb = blockIdx.y;
  const int tx = threadIdx.x, ty = threadIdx.y;
  if (z < 4) {
    const long b = z;
    const float* in = x + b * SS * DD;
    const int c0 = blockIdx.x * 32, r0 = yb * 32;  // c over D, r over S
#pragma unroll
    for (int i = 0; i < 32; i += 8) {
      float v = in[(long)(r0 + ty + i) * DD + c0 + tx];
      tile[ty + i][tx] = v;
      xb[(b * SS + r0 + ty + i) * DD + c0 + tx] = f2bf(v);
    }
    __syncthreads();
#pragma unroll
    for (int i = 0; i < 32; i += 8)
      xT[(b * DD + c0 + ty + i) * SS + r0 + tx] = f2bf(tile[tx][ty + i]);
  } else if (z < 7) {
    const int w = z - 4;
    if (yb < 16) {
      const float* in = w == 0 ? Wq : (w == 1 ? Wk : Wv);
      short* out = WT + (long)w * HH * DD;
      const int c0 = blockIdx.x * 32, r0 = yb * 32;
#pragma unroll
      for (int i = 0; i < 32; i += 8)
        tile[ty + i][tx] = in[(long)(r0 + ty + i) * HH + c0 + tx];
      __syncthreads();
#pragma unroll
      for (int i = 0; i < 32; i += 8)
        out[(long)(c0 + ty + i) * DD + r0 + tx] = f2bf(tile[tx][ty + i]);
    } else if (w == 0 && yb < 22 && blockIdx.x == 0) {
      const int i = (yb - 16) * 256 + ty * 32 + tx;
      bcat[i] = i < 512 ? bq[i] : (i < 1024 ? bk[i - 512] : bv[i - 1024]);
    }
  } else {
    const int c0 = blockIdx.x * 32, r0 = yb * 32;  // c over H, r over S
#pragma unroll
    for (int i = 0; i < 32; i += 8)
      tile[ty + i][tx] = Wd[(long)(r0 + ty + i) * HH + c0 + tx];
    __syncthreads();
#pragma unroll
    for (int i = 0; i < 32; i += 8)
      WdT[(long)(c0 + ty + i) * SS + r0 + tx] = f2bf(tile[tx][ty + i]);
  }
}

extern "C" void kernel_launch(void* const* d_in, const int* in_sizes, int n_in,
                              void* d_out, int out_size, void* d_ws,
                              size_t ws_size, hipStream_t stream) {
  (void)in_sizes;
  (void)n_in;
  (void)out_size;
  (void)ws_size;
  const float* x = (const float*)d_in[0];
  const float* Wq = (const float*)d_in[1];
  const float* bq = (const float*)d_in[2];
  const float* Wk = (const float*)d_in[3];
  const float* bk = (const float*)d_in[4];
  const float* Wv = (const float*)d_in[5];
  const float* bv = (const float*)d_in[6];
  const float* Wd = (const float*)d_in[7];
  const float* bd = (const float*)d_in[8];

  char* w = (char*)d_ws;
  auto alloc = [&](size_t bytes) {
    char* p = w;
    w += (bytes + 255) & ~(size_t)255;
    return p;
  };
  short* xb = (short*)alloc((size_t)BB * SS * DD * 2);        // 8MB
  short* xT = (short*)alloc((size_t)BB * DD * SS * 2);        // 8MB [b][D][S]
  short* WT = (short*)alloc((size_t)3 * HH * DD * 2);         // 1.5MB
  short* WdT = (short*)alloc((size_t)HH * SS * 2);            // 2MB
  float* bcat = (float*)alloc((size_t)3 * HH * 4);
  short* q = (short*)alloc((size_t)BB * SS * HH * 2);         // 8MB [b][S][H]
  short* kT = (short*)alloc((size_t)BB * HH * SS * 2);        // 8MB [b][H][S]
  short* vT = (short*)alloc((size_t)BB * HH * SS * 2);        // 8MB [b][H][S]
  short* partM2 = (short*)alloc((size_t)BB * 4 * HH * HH * 2);  // 8MB
  short* partM3 = (short*)alloc((size_t)BB * 4 * HH * HH * 2);  // 8MB
  short* M2 = (short*)alloc((size_t)BB * HH * HH * 2);        // 2MB
  short* M3t = (short*)alloc((size_t)BB * DD * HH * 2);       // 2MB
  short* dense = (short*)alloc((size_t)BB * SS * HH * 2);     // 8MB

  dim3 tb(32, 8);
  prep<<<dim3(16, 64, 8), tb, 0, stream>>>(x, Wq, Wk, Wv, Wd, bq, bk, bv, xb,
                                           xT, WT, WdT, bcat);

  // Stage 1: q/kT/vT = x @ [Wq|Wk|Wv] + bias, direct layouts
  gemm_qkv<<<dim3(BB * SS / 128, 12, 1), 256, 0, stream>>>(xb, WT, bcat, q, kT,
                                                           vT);
  // Stage 2a+3a split-K: partials for M2[b]=Wd^T@k[b], M3t[b]=x^T@v[b]
  gemm_dual_split<<<dim3(8, 4, 32), 256, 0, stream>>>(WdT, kT, partM2, xT, vT,
                                                      partM3);
  reduce_part<<<dim3(128, 1, 8), 256, 0, stream>>>(partM2, partM3, M2, M3t);
  // Stage 2b: dense = sigmoid(q @ M2^T + bd)   [2048,512] K=512, batch 4
  gemm_bt<64, 2><<<dim3(SS / 64, HH / 128, BB), 256, 0, stream>>>(
      q, M2, dense, bd, HH, HH, HH, HH, (long)SS * HH, (long)HH * HH,
      (long)SS * HH);
  // Stage 3b: out = dense @ M3t^T   [2048,512] K=512, batch 4, f32 out
  gemm_bt<64, 3><<<dim3(SS / 64, DD / 128, BB), 256, 0, stream>>>(
      dense, M3t, d_out, nullptr, HH, HH, HH, DD, (long)SS * HH, (long)DD * HH,
      (long)SS * DD);
}